// Round 1
// baseline (2388.534 us; speedup 1.0000x reference)
//
#include <hip/hip_runtime.h>
#include <math.h>

// Problem constants (fixed by setup_inputs)
#define DDIM 256      // feature dim D
#define WWIN 64       // window size
#define BDIM 8        // batch
#define LDIM 8192     // sequence length
#define NWIN 128      // L / W
#define SRCROWS 512   // B * W rows reduced per window

// ---------------------------------------------------------------------------
// K1: per-window weighted Gram sums.
//   Skk[n][d][e] = sum_{b,w} g * k_d * k_e
//   Svk[n][o][e] = sum_{b,w} g * v_o * k_e
// grid: NWIN * 4 tiles * 2 targets = 1024 blocks, 256 threads.
// Each block computes a 64-row x 256-col tile of one target matrix.
// ---------------------------------------------------------------------------
__global__ void sums_kernel(const float* __restrict__ keys,
                            const float* __restrict__ values,
                            const float* __restrict__ gammas,
                            float* __restrict__ Skk,
                            float* __restrict__ Svk) {
    int bi = blockIdx.x;
    int target = bi & 1;          // 0: Skk (A=keys), 1: Svk (A=values)
    int tile   = (bi >> 1) & 3;   // row tile 0..3
    int n      = bi >> 3;         // window
    int d0     = tile * 64;

    const float* Asrc = target ? values : keys;
    float* outp = target ? Svk : Skk;

    __shared__ float Ash[32][65];    // [src_row_chunk][row-dim col], padded
    __shared__ float Bsh[32][256];   // [src_row_chunk][k col]

    int t = threadIdx.x;
    int tcol = t & 63;    // lane within wave -> output col group
    int trow = t >> 6;    // wave id -> 16-row group

    float acc[16][4];
#pragma unroll
    for (int i = 0; i < 16; i++)
#pragma unroll
        for (int j = 0; j < 4; j++) acc[i][j] = 0.f;

    for (int r0 = 0; r0 < SRCROWS; r0 += 32) {
        __syncthreads();
        // stage A (g-weighted): 32 rows x 64 cols
#pragma unroll
        for (int i = 0; i < 8; i++) {
            int idx = t + i * 256;
            int row = idx >> 6;
            int col = idx & 63;
            int r = r0 + row;
            int b = r >> 6;
            int w = r & 63;
            int l = n * WWIN + w;
            float g = gammas[b * LDIM + l];
            Ash[row][col] = g * Asrc[((size_t)b * LDIM + l) * DDIM + d0 + col];
        }
        // stage B (k rows, full 256 cols)
#pragma unroll
        for (int row = 0; row < 32; row++) {
            int r = r0 + row;
            int b = r >> 6;
            int w = r & 63;
            int l = n * WWIN + w;
            Bsh[row][t] = keys[((size_t)b * LDIM + l) * DDIM + t];
        }
        __syncthreads();
#pragma unroll
        for (int rr = 0; rr < 32; rr++) {
            float bv[4];
#pragma unroll
            for (int j = 0; j < 4; j++) bv[j] = Bsh[rr][tcol + 64 * j];
#pragma unroll
            for (int i = 0; i < 16; i++) {
                float av = Ash[rr][trow * 16 + i];
#pragma unroll
                for (int j = 0; j < 4; j++) acc[i][j] += av * bv[j];
            }
        }
    }

#pragma unroll
    for (int i = 0; i < 16; i++)
#pragma unroll
        for (int j = 0; j < 4; j++)
            outp[((size_t)n * DDIM + (d0 + trow * 16 + i)) * DDIM + tcol + 64 * j] =
                acc[i][j];
}

// ---------------------------------------------------------------------------
// K2: one recurrence step. Dst = a*Src - Src@Op + Add  (all 256x256 f32)
// first=1: Dst = Add (M_{-1} = 0).
// grid: 64 blocks x 256 threads; block handles 4 output rows.
// ---------------------------------------------------------------------------
__global__ void step_kernel(const float* __restrict__ Src,
                            const float* __restrict__ Op,
                            const float* __restrict__ Add,
                            float* __restrict__ Dst,
                            const float* __restrict__ alpha_raw,
                            int first) {
    int t = threadIdx.x;
    int row0 = blockIdx.x * 4;
    if (first) {
#pragma unroll
        for (int i = 0; i < 4; i++)
            Dst[(size_t)(row0 + i) * DDIM + t] = Add[(size_t)(row0 + i) * DDIM + t];
        return;
    }
    float a = 1.f / (1.f + __expf(-alpha_raw[0]));
    __shared__ float S[4][256];
#pragma unroll
    for (int i = 0; i < 4; i++)
        S[i][t] = Src[(size_t)(row0 + i) * DDIM + t];
    __syncthreads();
    float acc[4] = {0.f, 0.f, 0.f, 0.f};
    for (int d = 0; d < DDIM; d++) {
        float o = Op[(size_t)d * DDIM + t];
#pragma unroll
        for (int i = 0; i < 4; i++) acc[i] += S[i][d] * o;
    }
#pragma unroll
    for (int i = 0; i < 4; i++)
        Dst[(size_t)(row0 + i) * DDIM + t] =
            a * S[i][t] - acc[i] + Add[(size_t)(row0 + i) * DDIM + t];
}

// ---------------------------------------------------------------------------
// K3: retrieval. out[b][l][o] = sum_d q[b][l][d] * Ms[n(l)][o][d]
// grid: B * NWIN = 1024 blocks, 256 threads; block computes 64x256 outputs.
// ---------------------------------------------------------------------------
__global__ void out_kernel(const float* __restrict__ queries,
                           const float* __restrict__ Ms,
                           float* __restrict__ out) {
    int bi = blockIdx.x;
    int n = bi & (NWIN - 1);
    int b = bi >> 7;

    const float* Mn = Ms + (size_t)n * DDIM * DDIM;
    int t = threadIdx.x;
    int tcol = t & 63;
    int trow = t >> 6;

    __shared__ float Qsh[64][32];    // [w][d-chunk]
    __shared__ float Msh[32][256];   // [d-chunk][o] (transposed stage)

    float acc[16][4];
#pragma unroll
    for (int i = 0; i < 16; i++)
#pragma unroll
        for (int j = 0; j < 4; j++) acc[i][j] = 0.f;

    for (int d0 = 0; d0 < DDIM; d0 += 32) {
        __syncthreads();
        // stage Q: 64 rows x 32 cols
#pragma unroll
        for (int i = 0; i < 8; i++) {
            int idx = t + i * 256;
            int w = idx >> 5;
            int dd = idx & 31;
            Qsh[w][dd] =
                queries[((size_t)b * LDIM + n * WWIN + w) * DDIM + d0 + dd];
        }
        // stage M transposed: Msh[dd][o] = Mn[o][d0+dd]
#pragma unroll
        for (int dd = 0; dd < 32; dd++)
            Msh[dd][t] = Mn[(size_t)t * DDIM + d0 + dd];
        __syncthreads();
#pragma unroll
        for (int dd = 0; dd < 32; dd++) {
            float bv[4];
#pragma unroll
            for (int j = 0; j < 4; j++) bv[j] = Msh[dd][tcol + 64 * j];
#pragma unroll
            for (int i = 0; i < 16; i++) {
                float av = Qsh[trow * 16 + i][dd];
#pragma unroll
                for (int j = 0; j < 4; j++) acc[i][j] += av * bv[j];
            }
        }
    }

#pragma unroll
    for (int i = 0; i < 16; i++) {
        int l = n * WWIN + trow * 16 + i;
#pragma unroll
        for (int j = 0; j < 4; j++)
            out[((size_t)b * LDIM + l) * DDIM + tcol + 64 * j] = acc[i][j];
    }
}

// ---------------------------------------------------------------------------
extern "C" void kernel_launch(void* const* d_in, const int* in_sizes, int n_in,
                              void* d_out, int out_size, void* d_ws, size_t ws_size,
                              hipStream_t stream) {
    const float* keys    = (const float*)d_in[0];
    const float* values  = (const float*)d_in[1];
    const float* queries = (const float*)d_in[2];
    const float* gammas  = (const float*)d_in[3];
    const float* alpha   = (const float*)d_in[4];
    float* outp = (float*)d_out;

    const size_t MAT = (size_t)DDIM * DDIM;      // 65536 floats
    float* ws  = (float*)d_ws;
    float* Skk = ws;                              // 128 * 64K f32 = 32 MB
    float* Svk = ws + (size_t)NWIN * MAT;         // 32 MB
    float* Ms  = ws + 2 * (size_t)NWIN * MAT;     // 32 MB

    // K1: all windows' Skk/Svk in parallel
    sums_kernel<<<NWIN * 8, 256, 0, stream>>>(keys, values, gammas, Skk, Svk);

    // K2: sequential scan over windows
    step_kernel<<<64, 256, 0, stream>>>(nullptr, nullptr, Svk, Ms, alpha, 1);
    for (int n = 1; n < NWIN; n++) {
        step_kernel<<<64, 256, 0, stream>>>(Ms + (size_t)(n - 1) * MAT,
                                            Skk + (size_t)n * MAT,
                                            Svk + (size_t)n * MAT,
                                            Ms + (size_t)n * MAT, alpha, 0);
    }

    // K3: retrieval
    out_kernel<<<BDIM * NWIN, 256, 0, stream>>>(queries, Ms, outp);
}

// Round 2
// 1720.785 us; speedup vs baseline: 1.3880x; 1.3880x over previous
//
#include <hip/hip_runtime.h>
#include <math.h>

// Problem constants (fixed by setup_inputs)
#define DDIM 256      // feature dim D
#define WWIN 64       // window size
#define BDIM 8        // batch
#define LDIM 8192     // sequence length
#define NWIN 128      // L / W
#define SRCROWS 512   // B * W rows reduced per window
#define CHUNK 8       // windows per scan chunk
#define NCHUNK 16     // NWIN / CHUNK
#define MAT ((size_t)DDIM * DDIM)

__device__ __forceinline__ float dev_sigmoid(float x) {
    return 1.f / (1.f + expf(-x));
}

// ---------------------------------------------------------------------------
// K1: per-window weighted Gram sums (unchanged from round 1).
//   Skk[n][d][e] = sum_{b,w} g * k_d * k_e
//   Svk[n][o][e] = sum_{b,w} g * v_o * k_e
// ---------------------------------------------------------------------------
__global__ void sums_kernel(const float* __restrict__ keys,
                            const float* __restrict__ values,
                            const float* __restrict__ gammas,
                            float* __restrict__ Skk,
                            float* __restrict__ Svk) {
    int bi = blockIdx.x;
    int target = bi & 1;
    int tile   = (bi >> 1) & 3;
    int n      = bi >> 3;
    int d0     = tile * 64;

    const float* Asrc = target ? values : keys;
    float* outp = target ? Svk : Skk;

    __shared__ float Ash[32][65];
    __shared__ float Bsh[32][256];

    int t = threadIdx.x;
    int tcol = t & 63;
    int trow = t >> 6;

    float acc[16][4];
#pragma unroll
    for (int i = 0; i < 16; i++)
#pragma unroll
        for (int j = 0; j < 4; j++) acc[i][j] = 0.f;

    for (int r0 = 0; r0 < SRCROWS; r0 += 32) {
        __syncthreads();
#pragma unroll
        for (int i = 0; i < 8; i++) {
            int idx = t + i * 256;
            int row = idx >> 6;
            int col = idx & 63;
            int r = r0 + row;
            int b = r >> 6;
            int w = r & 63;
            int l = n * WWIN + w;
            float g = gammas[b * LDIM + l];
            Ash[row][col] = g * Asrc[((size_t)b * LDIM + l) * DDIM + d0 + col];
        }
#pragma unroll
        for (int row = 0; row < 32; row++) {
            int r = r0 + row;
            int b = r >> 6;
            int w = r & 63;
            int l = n * WWIN + w;
            Bsh[row][t] = keys[((size_t)b * LDIM + l) * DDIM + t];
        }
        __syncthreads();
#pragma unroll
        for (int rr = 0; rr < 32; rr++) {
            float bv[4];
#pragma unroll
            for (int j = 0; j < 4; j++) bv[j] = Bsh[rr][tcol + 64 * j];
#pragma unroll
            for (int i = 0; i < 16; i++) {
                float av = Ash[rr][trow * 16 + i];
#pragma unroll
                for (int j = 0; j < 4; j++) acc[i][j] += av * bv[j];
            }
        }
    }

#pragma unroll
    for (int i = 0; i < 16; i++)
#pragma unroll
        for (int j = 0; j < 4; j++)
            outp[((size_t)n * DDIM + (d0 + trow * 16 + i)) * DDIM + tcol + 64 * j] =
                acc[i][j];
}

// ---------------------------------------------------------------------------
// Unified 16-row-tile 256x256 matmul:
//   Dst[r][c] = scale*A[r][c] + sgn*(A@B)[r][c] + (Add ? Add[r][c] : 0)
// Block covers rows [row0, row0+16) x all 256 cols. 256 threads,
// thread tile = 4 rows x 4 cols. Reads of A are restricted to the block's
// own 16 rows (safe for cross-slot in-place pipelines); Add/Dst tile-local
// (Add == Dst in-place is safe).
// ---------------------------------------------------------------------------
__device__ __forceinline__ void mm_tile16(const float* __restrict__ A,
                                          const float* __restrict__ B,
                                          const float* __restrict__ Add,
                                          float* __restrict__ Dst,
                                          int row0, float scale, float sgn) {
    __shared__ float Ash[16][33];
    __shared__ float Bsh[32][256];

    int t = threadIdx.x;
    int tcol = t & 63;   // -> cols tcol*4 .. +3
    int trow = t >> 6;   // -> rows trow*4 .. +3 (wave-uniform => LDS broadcast)

    float acc[4][4];
#pragma unroll
    for (int i = 0; i < 4; i++)
#pragma unroll
        for (int j = 0; j < 4; j++) acc[i][j] = 0.f;

    for (int k0 = 0; k0 < DDIM; k0 += 32) {
        __syncthreads();
        {   // stage A tile: 16 rows x 32 k, coalesced float2
            int row = t >> 4;
            int kk = (t & 15) * 2;
            float2 v = *(const float2*)&A[(size_t)(row0 + row) * DDIM + k0 + kk];
            Ash[row][kk] = v.x;
            Ash[row][kk + 1] = v.y;
        }
#pragma unroll
        for (int p = 0; p < 8; p++) {  // stage B: 32 k-rows x 256 cols, float4
            int row = (t >> 6) + p * 4;
            int c4 = (t & 63) * 4;
            *(float4*)&Bsh[row][c4] =
                *(const float4*)&B[(size_t)(k0 + row) * DDIM + c4];
        }
        __syncthreads();
#pragma unroll
        for (int kk = 0; kk < 32; kk++) {
            float4 bv = *(const float4*)&Bsh[kk][tcol * 4];
#pragma unroll
            for (int i = 0; i < 4; i++) {
                float av = Ash[trow * 4 + i][kk];
                acc[i][0] += av * bv.x;
                acc[i][1] += av * bv.y;
                acc[i][2] += av * bv.z;
                acc[i][3] += av * bv.w;
            }
        }
    }

#pragma unroll
    for (int i = 0; i < 4; i++) {
        int r = row0 + trow * 4 + i;
        float4 av = *(const float4*)&A[(size_t)r * DDIM + tcol * 4];
        float4 o;
        o.x = scale * av.x + sgn * acc[i][0];
        o.y = scale * av.y + sgn * acc[i][1];
        o.z = scale * av.z + sgn * acc[i][2];
        o.w = scale * av.w + sgn * acc[i][3];
        if (Add) {
            float4 ad = *(const float4*)&Add[(size_t)r * DDIM + tcol * 4];
            o.x += ad.x; o.y += ad.y; o.z += ad.z; o.w += ad.w;
        }
        *(float4*)&Dst[(size_t)r * DDIM + tcol * 4] = o;
    }
}

// ---------------------------------------------------------------------------
// Scan phase 0: P_0 = a*I - Skk[chunk start] for each chunk.
// grid 1024 x 256, float4 element-wise.
// ---------------------------------------------------------------------------
__global__ void pinit_kernel(const float* __restrict__ Skk,
                             float* __restrict__ P,
                             const float* __restrict__ alpha_raw) {
    float a = dev_sigmoid(alpha_raw[0]);
    int cm = blockIdx.x >> 6;                   // chunk 0..15
    size_t e = (size_t)(blockIdx.x & 63) * 1024 + threadIdx.x * 4;
    size_t base = (size_t)(cm * CHUNK) * MAT + e;
    int row = (int)(e >> 8);
    int col = (int)(e & 255);
    float4 v = *(const float4*)&Skk[base];
    float4 o;
    o.x = ((row == col)     ? a : 0.f) - v.x;
    o.y = ((row == col + 1) ? a : 0.f) - v.y;
    o.z = ((row == col + 2) ? a : 0.f) - v.z;
    o.w = ((row == col + 3) ? a : 0.f) - v.w;
    *(float4*)&P[base] = o;
}

// ---------------------------------------------------------------------------
// Scan phase 1, step j (j=1..CHUNK-1), all chunks in parallel:
//   P_n = a*P_{n-1} - P_{n-1}@Skk_n                 (target 0)
//   Q_n = a*Q_{n-1} - Q_{n-1}@Skk_n + Svk_n (inpl)  (target 1)
// grid = NCHUNK*2*16 = 512 blocks.
// ---------------------------------------------------------------------------
__global__ void phase1_kernel(const float* __restrict__ Skk,
                              float* __restrict__ Q,
                              float* __restrict__ P,
                              const float* __restrict__ alpha_raw,
                              int j) {
    float a = dev_sigmoid(alpha_raw[0]);
    int tile = blockIdx.x & 15;
    int idx = blockIdx.x >> 4;     // 0..31
    int chunk = idx >> 1;
    int target = idx & 1;
    int n = chunk * CHUNK + j;
    const float* Bm = Skk + (size_t)n * MAT;
    if (target == 0) {
        mm_tile16(P + (size_t)(n - 1) * MAT, Bm, nullptr,
                  P + (size_t)n * MAT, tile * 16, a, -1.f);
    } else {
        float* d = Q + (size_t)n * MAT;
        mm_tile16(Q + (size_t)(n - 1) * MAT, Bm, d, d, tile * 16, a, -1.f);
    }
}

// ---------------------------------------------------------------------------
// Scan phase 2, step c (c=1..NCHUNK-1), sequential:
//   M_e = M_s @ P_e + Q_e (in place over Q_e), e=(c+1)*CHUNK-1, s=c*CHUNK-1.
// grid = 16 blocks.
// ---------------------------------------------------------------------------
__global__ void phase2_kernel(float* __restrict__ Q,
                              const float* __restrict__ P,
                              int c) {
    int e = (c + 1) * CHUNK - 1;
    int s = c * CHUNK - 1;
    float* d = Q + (size_t)e * MAT;
    mm_tile16(Q + (size_t)s * MAT, P + (size_t)e * MAT, d, d,
              blockIdx.x * 16, 0.f, 1.f);
}

// ---------------------------------------------------------------------------
// Scan phase 3: all remaining windows in parallel:
//   M_n = M_s @ P_n + Q_n (in place), c=1..15, j=0..CHUNK-2, s=c*CHUNK-1.
// grid = 15*7*16 = 1680 blocks.
// ---------------------------------------------------------------------------
__global__ void phase3_kernel(float* __restrict__ Q,
                              const float* __restrict__ P) {
    int tile = blockIdx.x & 15;
    int w = blockIdx.x >> 4;       // 0..104
    int c = 1 + w / (CHUNK - 1);
    int j = w - (c - 1) * (CHUNK - 1);
    int n = c * CHUNK + j;
    int s = c * CHUNK - 1;
    float* d = Q + (size_t)n * MAT;
    mm_tile16(Q + (size_t)s * MAT, P + (size_t)n * MAT, d, d,
              tile * 16, 0.f, 1.f);
}

// ---------------------------------------------------------------------------
// K3: retrieval. out[b][l][o] = sum_d q[b][l][d] * Ms[n(l)][o][d]
// Fixed M staging: coalesced global reads + LDS transpose (stride 257,
// conflict-free banks both directions).
// ---------------------------------------------------------------------------
__global__ void out_kernel(const float* __restrict__ queries,
                           const float* __restrict__ Ms,
                           float* __restrict__ out) {
    int bi = blockIdx.x;
    int n = bi & (NWIN - 1);
    int b = bi >> 7;

    const float* Mn = Ms + (size_t)n * MAT;
    int t = threadIdx.x;
    int tcol = t & 63;
    int trow = t >> 6;

    __shared__ float Qsh[64][32];        // [w][dd]  (reads are broadcast)
    __shared__ float MshT[32 * 257];     // [dd][o], row stride 257

    float acc[16][4];
#pragma unroll
    for (int i = 0; i < 16; i++)
#pragma unroll
        for (int j = 0; j < 4; j++) acc[i][j] = 0.f;

    for (int d0 = 0; d0 < DDIM; d0 += 32) {
        __syncthreads();
        // stage Q: 64 w x 32 dd, coalesced
#pragma unroll
        for (int p = 0; p < 8; p++) {
            int w = (t >> 5) + p * 8;
            int dd = t & 31;
            Qsh[w][dd] =
                queries[((size_t)b * LDIM + n * WWIN + w) * DDIM + d0 + dd];
        }
        // stage M transposed: coalesced global read, conflict-free LDS write
#pragma unroll
        for (int p = 0; p < 32; p++) {
            int o = (t >> 5) + p * 8;
            int dd = t & 31;
            MshT[dd * 257 + o] = Mn[(size_t)o * DDIM + d0 + dd];
        }
        __syncthreads();
#pragma unroll
        for (int dd = 0; dd < 32; dd++) {
            float bv[4];
#pragma unroll
            for (int j = 0; j < 4; j++) bv[j] = MshT[dd * 257 + tcol + 64 * j];
#pragma unroll
            for (int i = 0; i < 16; i++) {
                float av = Qsh[trow * 16 + i][dd];
#pragma unroll
                for (int j = 0; j < 4; j++) acc[i][j] += av * bv[j];
            }
        }
    }

#pragma unroll
    for (int i = 0; i < 16; i++) {
        int l = n * WWIN + trow * 16 + i;
#pragma unroll
        for (int j = 0; j < 4; j++)
            out[((size_t)b * LDIM + l) * DDIM + tcol + 64 * j] = acc[i][j];
    }
}

// ---------------------------------------------------------------------------
extern "C" void kernel_launch(void* const* d_in, const int* in_sizes, int n_in,
                              void* d_out, int out_size, void* d_ws, size_t ws_size,
                              hipStream_t stream) {
    const float* keys    = (const float*)d_in[0];
    const float* values  = (const float*)d_in[1];
    const float* queries = (const float*)d_in[2];
    const float* gammas  = (const float*)d_in[3];
    const float* alpha   = (const float*)d_in[4];
    float* outp = (float*)d_out;

    float* ws  = (float*)d_ws;
    float* Skk = ws;                              // 32 MB
    float* Q   = ws + (size_t)NWIN * MAT;         // 32 MB: Svk -> Q prefixes -> final Ms
    float* P   = ws + 2 * (size_t)NWIN * MAT;     // 32 MB: P prefixes

    // K1: all windows' Skk/Svk in parallel
    sums_kernel<<<NWIN * 8, 256, 0, stream>>>(keys, values, gammas, Skk, Q);

    // Scan phase 0: chunk-start P
    pinit_kernel<<<1024, 256, 0, stream>>>(Skk, P, alpha);

    // Scan phase 1: within-chunk prefixes (7 sequential steps, chunks parallel)
    for (int j = 1; j < CHUNK; j++)
        phase1_kernel<<<NCHUNK * 2 * 16, 256, 0, stream>>>(Skk, Q, P, alpha, j);

    // Scan phase 2: chunk boundaries (15 sequential tiny matmuls)
    for (int c = 1; c < NCHUNK; c++)
        phase2_kernel<<<16, 256, 0, stream>>>(Q, P, c);

    // Scan phase 3: all remaining windows in parallel
    phase3_kernel<<<(NCHUNK - 1) * (CHUNK - 1) * 16, 256, 0, stream>>>(Q, P);

    // K3: retrieval (Ms now lives in Q)
    out_kernel<<<BDIM * NWIN, 256, 0, stream>>>(queries, Q, outp);
}

// Round 3
// 906.476 us; speedup vs baseline: 2.6350x; 1.8983x over previous
//
#include <hip/hip_runtime.h>
#include <math.h>

typedef unsigned short ushortT;
typedef unsigned int uintT;
typedef __attribute__((ext_vector_type(8))) short short8;
typedef __attribute__((ext_vector_type(4))) float floatx4;

// Problem constants
#define DDIM 256
#define WWIN 64
#define BDIM 8
#define LDIM 8192
#define NWIN 128
#define CHUNK 8
#define NCHUNK 16
#define MAT ((size_t)DDIM * DDIM)
#define RWIN 512          // B * WWIN rows per window

__device__ __forceinline__ float dev_sigmoid(float x) {
    return 1.f / (1.f + expf(-x));
}

// f32 -> bf16 round-to-nearest-even
__device__ __forceinline__ ushortT f2b(float f) {
    uintT u = __float_as_uint(f);
    u += 0x7fff + ((u >> 16) & 1);
    return (ushortT)(u >> 16);
}

// ---------------------------------------------------------------------------
// Transpose keys -> Tk[n][d][r] bf16, Tgk[n][d][r] = (g*k)^T bf16.
// r = b*64 + w within window n. grid = NWIN*BDIM blocks, 256 threads (d = tid).
// Global reads: per instr the block reads one l-row's 256 floats (coalesced).
// ---------------------------------------------------------------------------
__global__ void transpose_keys(const float* __restrict__ keys,
                               const float* __restrict__ gammas,
                               ushortT* __restrict__ Tk,
                               ushortT* __restrict__ Tgk) {
    int b = blockIdx.x & 7;
    int n = blockIdx.x >> 3;
    int d = threadIdx.x;
    size_t inbase = ((size_t)b * LDIM + n * WWIN) * DDIM + d;
    size_t gbase = (size_t)b * LDIM + n * WWIN;
    size_t outbase = ((size_t)n * DDIM + d) * RWIN + b * WWIN;
#pragma unroll
    for (int wg = 0; wg < 8; wg++) {
        uintT pk[4], pg[4];
#pragma unroll
        for (int i = 0; i < 4; i++) {
            int w0 = wg * 8 + i * 2;
            float k0 = keys[inbase + (size_t)w0 * DDIM];
            float k1 = keys[inbase + (size_t)(w0 + 1) * DDIM];
            float g0 = gammas[gbase + w0];
            float g1 = gammas[gbase + w0 + 1];
            pk[i] = (uintT)f2b(k0) | ((uintT)f2b(k1) << 16);
            pg[i] = (uintT)f2b(g0 * k0) | ((uintT)f2b(g1 * k1) << 16);
        }
        uint4 a; a.x = pk[0]; a.y = pk[1]; a.z = pk[2]; a.w = pk[3];
        uint4 g4; g4.x = pg[0]; g4.y = pg[1]; g4.z = pg[2]; g4.w = pg[3];
        *(uint4*)&Tk[outbase + wg * 8] = a;
        *(uint4*)&Tgk[outbase + wg * 8] = g4;
    }
}

// Same for values -> Tv (no gamma).
__global__ void transpose_vals(const float* __restrict__ values,
                               ushortT* __restrict__ Tv) {
    int b = blockIdx.x & 7;
    int n = blockIdx.x >> 3;
    int d = threadIdx.x;
    size_t inbase = ((size_t)b * LDIM + n * WWIN) * DDIM + d;
    size_t outbase = ((size_t)n * DDIM + d) * RWIN + b * WWIN;
#pragma unroll
    for (int wg = 0; wg < 8; wg++) {
        uintT pk[4];
#pragma unroll
        for (int i = 0; i < 4; i++) {
            int w0 = wg * 8 + i * 2;
            float k0 = values[inbase + (size_t)w0 * DDIM];
            float k1 = values[inbase + (size_t)(w0 + 1) * DDIM];
            pk[i] = (uintT)f2b(k0) | ((uintT)f2b(k1) << 16);
        }
        uint4 a; a.x = pk[0]; a.y = pk[1]; a.z = pk[2]; a.w = pk[3];
        *(uint4*)&Tv[outbase + wg * 8] = a;
    }
}

// ---------------------------------------------------------------------------
// MFMA sums GEMM: Out[n][m][e] = sum_r At[n][m][r] * Bt[n][e][r]  (f32 accum)
// Block: 128x128 tile of one window. 4 waves of 64x64 (4x4 16x16 frags).
// grid = NWIN * 2(mq) * 2(nq).
// ---------------------------------------------------------------------------
__global__ __launch_bounds__(256, 2) void sums_mfma(
    const ushortT* __restrict__ At,
    const ushortT* __restrict__ Bt,
    float* __restrict__ Out) {
    int nq = blockIdx.x & 1;
    int mq = (blockIdx.x >> 1) & 1;
    int n = blockIdx.x >> 2;

    const ushortT* Ab = At + (size_t)n * DDIM * RWIN + (size_t)(mq * 128) * RWIN;
    const ushortT* Bb = Bt + (size_t)n * DDIM * RWIN + (size_t)(nq * 128) * RWIN;

    __shared__ __align__(16) ushortT Asm[128 * 64];
    __shared__ __align__(16) ushortT Bsm[128 * 64];

    int t = threadIdx.x;
    int lane = t & 63, wv = t >> 6;
    int wm = (wv & 1) * 64, wn = (wv >> 1) * 64;
    int m16 = lane & 15, g = lane >> 4;

    floatx4 acc[4][4];
#pragma unroll
    for (int i = 0; i < 4; i++)
#pragma unroll
        for (int j = 0; j < 4; j++) acc[i][j] = (floatx4)0.f;

    for (int c = 0; c < 8; c++) {
        int r0 = c * 64;
        __syncthreads();
#pragma unroll
        for (int p = 0; p < 4; p++) {
            int row = (t >> 3) + p * 32;
            int rg = t & 7;
            *(uint4*)&Asm[row * 64 + rg * 8] =
                *(const uint4*)&Ab[(size_t)row * RWIN + r0 + rg * 8];
            *(uint4*)&Bsm[row * 64 + rg * 8] =
                *(const uint4*)&Bb[(size_t)row * RWIN + r0 + rg * 8];
        }
        __syncthreads();
#pragma unroll
        for (int ks = 0; ks < 2; ks++) {
            short8 af[4], bf[4];
#pragma unroll
            for (int i = 0; i < 4; i++)
                af[i] = *(const short8*)&Asm[(wm + i * 16 + m16) * 64 + ks * 32 + g * 8];
#pragma unroll
            for (int j = 0; j < 4; j++)
                bf[j] = *(const short8*)&Bsm[(wn + j * 16 + m16) * 64 + ks * 32 + g * 8];
#pragma unroll
            for (int i = 0; i < 4; i++)
#pragma unroll
                for (int j = 0; j < 4; j++)
                    acc[i][j] = __builtin_amdgcn_mfma_f32_16x16x32_bf16(
                        af[i], bf[j], acc[i][j], 0, 0, 0);
        }
    }

    float* Ob = Out + (size_t)n * MAT;
#pragma unroll
    for (int i = 0; i < 4; i++)
#pragma unroll
        for (int j = 0; j < 4; j++)
#pragma unroll
            for (int r = 0; r < 4; r++) {
                int row = mq * 128 + wm + i * 16 + g * 4 + r;
                int col = nq * 128 + wn + j * 16 + m16;
                Ob[(size_t)row * DDIM + col] = acc[i][j][r];
            }
}

// ---------------------------------------------------------------------------
// Convert scan result Q (f32) -> Mb (bf16). grid = 4096 x 256, 8 el/thread.
// ---------------------------------------------------------------------------
__global__ void convert_m(const float* __restrict__ Q, ushortT* __restrict__ Mb) {
    size_t i = ((size_t)blockIdx.x * 256 + threadIdx.x) * 8;
    float4 a = *(const float4*)&Q[i];
    float4 b = *(const float4*)&Q[i + 4];
    uint4 o;
    o.x = (uintT)f2b(a.x) | ((uintT)f2b(a.y) << 16);
    o.y = (uintT)f2b(a.z) | ((uintT)f2b(a.w) << 16);
    o.z = (uintT)f2b(b.x) | ((uintT)f2b(b.y) << 16);
    o.w = (uintT)f2b(b.z) | ((uintT)f2b(b.w) << 16);
    *(uint4*)&Mb[i] = o;
}

// ---------------------------------------------------------------------------
// MFMA retrieval: out[l][o] = sum_d q[l][d] * M[n(l)][o][d]
// Block: 128 q-rows x 128 o for one window. grid = NWIN * 4(rp) * 2(op).
// ---------------------------------------------------------------------------
__global__ __launch_bounds__(256, 2) void out_mfma(
    const float* __restrict__ q,
    const ushortT* __restrict__ Mb,
    float* __restrict__ out) {
    int op = blockIdx.x & 1;
    int rp = (blockIdx.x >> 1) & 3;
    int n = blockIdx.x >> 3;

    __shared__ __align__(16) ushortT Qsm[128 * 64];
    __shared__ __align__(16) ushortT Msm[128 * 64];

    int t = threadIdx.x;
    int lane = t & 63, wv = t >> 6;
    int wm = (wv & 1) * 64, wn = (wv >> 1) * 64;
    int m16 = lane & 15, g = lane >> 4;

    const ushortT* Mbase = Mb + (size_t)n * MAT + (size_t)(op * 128) * DDIM;

    floatx4 acc[4][4];
#pragma unroll
    for (int i = 0; i < 4; i++)
#pragma unroll
        for (int j = 0; j < 4; j++) acc[i][j] = (floatx4)0.f;

    for (int c = 0; c < 4; c++) {
        int d0 = c * 64;
        __syncthreads();
        // stage q: 128 rows x 64 d, f32->bf16
#pragma unroll
        for (int p = 0; p < 8; p++) {
            int row = (t >> 4) + p * 16;
            int f4 = t & 15;
            int b = rp * 2 + (row >> 6);
            int l = b * LDIM + n * WWIN + (row & 63);
            float4 v = *(const float4*)&q[(size_t)l * DDIM + d0 + f4 * 4];
            uint2 o;
            o.x = (uintT)f2b(v.x) | ((uintT)f2b(v.y) << 16);
            o.y = (uintT)f2b(v.z) | ((uintT)f2b(v.w) << 16);
            *(uint2*)&Qsm[row * 64 + f4 * 4] = o;
        }
        // stage M: 128 o x 64 d (bf16 direct)
#pragma unroll
        for (int p = 0; p < 4; p++) {
            int o = (t >> 3) + p * 32;
            int dg = t & 7;
            *(uint4*)&Msm[o * 64 + dg * 8] =
                *(const uint4*)&Mbase[(size_t)o * DDIM + d0 + dg * 8];
        }
        __syncthreads();
#pragma unroll
        for (int ks = 0; ks < 2; ks++) {
            short8 af[4], bf[4];
#pragma unroll
            for (int i = 0; i < 4; i++)
                af[i] = *(const short8*)&Qsm[(wm + i * 16 + m16) * 64 + ks * 32 + g * 8];
#pragma unroll
            for (int j = 0; j < 4; j++)
                bf[j] = *(const short8*)&Msm[(wn + j * 16 + m16) * 64 + ks * 32 + g * 8];
#pragma unroll
            for (int i = 0; i < 4; i++)
#pragma unroll
                for (int j = 0; j < 4; j++)
                    acc[i][j] = __builtin_amdgcn_mfma_f32_16x16x32_bf16(
                        af[i], bf[j], acc[i][j], 0, 0, 0);
        }
    }

#pragma unroll
    for (int i = 0; i < 4; i++)
#pragma unroll
        for (int r = 0; r < 4; r++) {
            int row = wm + i * 16 + g * 4 + r;
            int b = rp * 2 + (row >> 6);
            size_t l = (size_t)b * LDIM + n * WWIN + (row & 63);
#pragma unroll
            for (int j = 0; j < 4; j++) {
                int col = op * 128 + wn + j * 16 + m16;
                out[l * DDIM + col] = acc[i][j][r];
            }
        }
}

// ---------------------------------------------------------------------------
// Scan (unchanged f32 machinery from round 2)
// ---------------------------------------------------------------------------
__device__ __forceinline__ void mm_tile16(const float* __restrict__ A,
                                          const float* __restrict__ B,
                                          const float* __restrict__ Add,
                                          float* __restrict__ Dst,
                                          int row0, float scale, float sgn) {
    __shared__ float Ash[16][33];
    __shared__ float Bsh[32][256];

    int t = threadIdx.x;
    int tcol = t & 63;
    int trow = t >> 6;

    float acc[4][4];
#pragma unroll
    for (int i = 0; i < 4; i++)
#pragma unroll
        for (int j = 0; j < 4; j++) acc[i][j] = 0.f;

    for (int k0 = 0; k0 < DDIM; k0 += 32) {
        __syncthreads();
        {
            int row = t >> 4;
            int kk = (t & 15) * 2;
            float2 v = *(const float2*)&A[(size_t)(row0 + row) * DDIM + k0 + kk];
            Ash[row][kk] = v.x;
            Ash[row][kk + 1] = v.y;
        }
#pragma unroll
        for (int p = 0; p < 8; p++) {
            int row = (t >> 6) + p * 4;
            int c4 = (t & 63) * 4;
            *(float4*)&Bsh[row][c4] =
                *(const float4*)&B[(size_t)(k0 + row) * DDIM + c4];
        }
        __syncthreads();
#pragma unroll
        for (int kk = 0; kk < 32; kk++) {
            float4 bv = *(const float4*)&Bsh[kk][tcol * 4];
#pragma unroll
            for (int i = 0; i < 4; i++) {
                float av = Ash[trow * 4 + i][kk];
                acc[i][0] += av * bv.x;
                acc[i][1] += av * bv.y;
                acc[i][2] += av * bv.z;
                acc[i][3] += av * bv.w;
            }
        }
    }

#pragma unroll
    for (int i = 0; i < 4; i++) {
        int r = row0 + trow * 4 + i;
        float4 av = *(const float4*)&A[(size_t)r * DDIM + tcol * 4];
        float4 o;
        o.x = scale * av.x + sgn * acc[i][0];
        o.y = scale * av.y + sgn * acc[i][1];
        o.z = scale * av.z + sgn * acc[i][2];
        o.w = scale * av.w + sgn * acc[i][3];
        if (Add) {
            float4 ad = *(const float4*)&Add[(size_t)r * DDIM + tcol * 4];
            o.x += ad.x; o.y += ad.y; o.z += ad.z; o.w += ad.w;
        }
        *(float4*)&Dst[(size_t)r * DDIM + tcol * 4] = o;
    }
}

__global__ void pinit_kernel(const float* __restrict__ Skk,
                             float* __restrict__ P,
                             const float* __restrict__ alpha_raw) {
    float a = dev_sigmoid(alpha_raw[0]);
    int cm = blockIdx.x >> 6;
    size_t e = (size_t)(blockIdx.x & 63) * 1024 + threadIdx.x * 4;
    size_t base = (size_t)(cm * CHUNK) * MAT + e;
    int row = (int)(e >> 8);
    int col = (int)(e & 255);
    float4 v = *(const float4*)&Skk[base];
    float4 o;
    o.x = ((row == col)     ? a : 0.f) - v.x;
    o.y = ((row == col + 1) ? a : 0.f) - v.y;
    o.z = ((row == col + 2) ? a : 0.f) - v.z;
    o.w = ((row == col + 3) ? a : 0.f) - v.w;
    *(float4*)&P[base] = o;
}

__global__ void phase1_kernel(const float* __restrict__ Skk,
                              float* __restrict__ Q,
                              float* __restrict__ P,
                              const float* __restrict__ alpha_raw,
                              int j) {
    float a = dev_sigmoid(alpha_raw[0]);
    int tile = blockIdx.x & 15;
    int idx = blockIdx.x >> 4;
    int chunk = idx >> 1;
    int target = idx & 1;
    int n = chunk * CHUNK + j;
    const float* Bm = Skk + (size_t)n * MAT;
    if (target == 0) {
        mm_tile16(P + (size_t)(n - 1) * MAT, Bm, nullptr,
                  P + (size_t)n * MAT, tile * 16, a, -1.f);
    } else {
        float* d = Q + (size_t)n * MAT;
        mm_tile16(Q + (size_t)(n - 1) * MAT, Bm, d, d, tile * 16, a, -1.f);
    }
}

__global__ void phase2_kernel(float* __restrict__ Q,
                              const float* __restrict__ P,
                              int c) {
    int e = (c + 1) * CHUNK - 1;
    int s = c * CHUNK - 1;
    float* d = Q + (size_t)e * MAT;
    mm_tile16(Q + (size_t)s * MAT, P + (size_t)e * MAT, d, d,
              blockIdx.x * 16, 0.f, 1.f);
}

__global__ void phase3_kernel(float* __restrict__ Q,
                              const float* __restrict__ P) {
    int tile = blockIdx.x & 15;
    int w = blockIdx.x >> 4;
    int c = 1 + w / (CHUNK - 1);
    int j = w - (c - 1) * (CHUNK - 1);
    int n = c * CHUNK + j;
    int s = c * CHUNK - 1;
    float* d = Q + (size_t)n * MAT;
    mm_tile16(Q + (size_t)s * MAT, P + (size_t)n * MAT, d, d,
              tile * 16, 0.f, 1.f);
}

// ---------------------------------------------------------------------------
extern "C" void kernel_launch(void* const* d_in, const int* in_sizes, int n_in,
                              void* d_out, int out_size, void* d_ws, size_t ws_size,
                              hipStream_t stream) {
    const float* keys    = (const float*)d_in[0];
    const float* values  = (const float*)d_in[1];
    const float* queries = (const float*)d_in[2];
    const float* gammas  = (const float*)d_in[3];
    const float* alpha   = (const float*)d_in[4];
    float* outp = (float*)d_out;

    // Workspace layout (128 MB peak):
    //  A [0,32M):   Skk f32
    //  B [32,64M):  Q f32 (Svk -> prefix -> final Ms)
    //  C [64,96M):  Tk bf16, then Tv bf16, then P f32
    //  D [96,128M): Tgk bf16, then Mb bf16
    char* ws = (char*)d_ws;
    float*   Skk = (float*)ws;
    float*   Q   = (float*)(ws + (size_t)32 * 1024 * 1024);
    char*    rC  = ws + (size_t)64 * 1024 * 1024;
    char*    rD  = ws + (size_t)96 * 1024 * 1024;
    ushortT* Tk  = (ushortT*)rC;
    ushortT* Tv  = (ushortT*)rC;
    float*   P   = (float*)rC;
    ushortT* Tgk = (ushortT*)rD;
    ushortT* Mb  = (ushortT*)rD;

    // 1) transpose keys -> Tk, Tgk
    transpose_keys<<<NWIN * BDIM, 256, 0, stream>>>(keys, gammas, Tk, Tgk);
    // 2) Skk = Tk (x) Tgk
    sums_mfma<<<NWIN * 4, 256, 0, stream>>>(Tk, Tgk, Skk);
    // 3) transpose values -> Tv (overwrites Tk)
    transpose_vals<<<NWIN * BDIM, 256, 0, stream>>>(values, Tv);
    // 4) Svk = Tv (x) Tgk -> Q
    sums_mfma<<<NWIN * 4, 256, 0, stream>>>(Tv, Tgk, Q);

    // 5) scan (f32, unchanged); P overwrites Tv/Tk region
    pinit_kernel<<<1024, 256, 0, stream>>>(Skk, P, alpha);
    for (int j = 1; j < CHUNK; j++)
        phase1_kernel<<<NCHUNK * 2 * 16, 256, 0, stream>>>(Skk, Q, P, alpha, j);
    for (int c = 1; c < NCHUNK; c++)
        phase2_kernel<<<16, 256, 0, stream>>>(Q, P, c);
    phase3_kernel<<<(NCHUNK - 1) * (CHUNK - 1) * 16, 256, 0, stream>>>(Q, P);

    // 6) M -> bf16 (overwrites Tgk region)
    convert_m<<<4096, 256, 0, stream>>>(Q, Mb);

    // 7) retrieval
    out_mfma<<<NWIN * 8, 256, 0, stream>>>(queries, Mb, outp);
}